// Round 5
// baseline (196.744 us; speedup 1.0000x reference)
//
#include <hip/hip_runtime.h>
#include <hip/hip_bf16.h>
#include <stdint.h>

// Problem constants
constexpr int B    = 8;
constexpr int T    = 2048;
constexpr int EMB  = 2048;
constexpr int HD   = 128;
constexpr int M    = B * T;        // 16384 rows for projection GEMM
constexpr int NW   = 3 * HD;       // 384 fused output cols (Q|K|V)

typedef __attribute__((ext_vector_type(8))) short short8;
typedef __attribute__((ext_vector_type(4))) float f32x4;

__device__ inline unsigned short f2bf(float f) {
    union { float f; unsigned int u; } v; v.f = f;
    unsigned int x = v.u;
    unsigned int r = (x + 0x7FFFu + ((x >> 16) & 1u)) >> 16;   // RNE
    return (unsigned short)r;
}

// ---------------------------------------------------------------------------
// Kernel 0: convert Wq|Wk|Wv fp32 -> bf16 into Wb[384][2048]
// ---------------------------------------------------------------------------
__global__ __launch_bounds__(256) void conv_w(
    const float* __restrict__ Wq, const float* __restrict__ Wk, const float* __restrict__ Wv,
    unsigned short* __restrict__ Wb)
{
    int base = (blockIdx.x * 256 + threadIdx.x) * 8;   // < 384*2048
    int row = base >> 11, col = base & 2047;
    const float* src;
    if (row < 128)      src = Wq + (size_t)row * EMB + col;
    else if (row < 256) src = Wk + (size_t)(row - 128) * EMB + col;
    else                src = Wv + (size_t)(row - 256) * EMB + col;
    float4 a = *(const float4*)src;
    float4 b = *(const float4*)(src + 4);
    short8 sv;
    sv[0] = f2bf(a.x); sv[1] = f2bf(a.y); sv[2] = f2bf(a.z); sv[3] = f2bf(a.w);
    sv[4] = f2bf(b.x); sv[5] = f2bf(b.y); sv[6] = f2bf(b.z); sv[7] = f2bf(b.w);
    *(short8*)(Wb + base) = sv;
}

// ---------------------------------------------------------------------------
// Kernel 1: fused QKV projection, occupancy-first 2-phase pipeline.
// Tile 16(M) x 384(N=full), BK=32, 64 K-steps. Grid 1024 -> 3 blocks/CU
// (LDS 50 KB) = 12 waves/CU. 256 thr = 4 waves; wave w covers cols w*96..+95,
// all 16 rows: 6 16x16 frags, 6 MFMA/step.
// A (x fp32): reg-staged (float2/thread), cvt at WRITE (2 f2bf/thread/step).
// B (Wb bf16): global_load_lds direct, 6 x 16B/thread, no cvt, no VGPR trip.
// Q,K written [M][128] bf16; V written TRANSPOSED [B][128][T] bf16.
// ---------------------------------------------------------------------------
constexpr int PBM = 16;
constexpr int PBK = 32;
constexpr int PNT = EMB / PBK;   // 64

__global__ __launch_bounds__(256) void qkv_proj(
    const float* __restrict__ x, const unsigned short* __restrict__ Wb,
    unsigned short* __restrict__ Qb, unsigned short* __restrict__ Kb,
    unsigned short* __restrict__ VtG)
{
    __shared__ unsigned short As[2][PBM * PBK];   // 2 x 1 KB bf16
    __shared__ unsigned short Bs[2][NW * PBK];    // 2 x 24 KB bf16

    const int m0   = blockIdx.x * PBM;
    const int tid  = threadIdx.x;
    const int lane = tid & 63;
    const int w    = tid >> 6;           // 0..3
    const int lo   = lane & 15;
    const int hi   = lane >> 4;

    // A staging coords: thread -> (row 0..15, 2-float col)
    const int arow = tid >> 4;
    const int ac2  = (tid & 15) * 2;
    const float* asrc = x + (size_t)(m0 + arow) * EMB + ac2;

    f32x4 acc[6];
#pragma unroll
    for (int j = 0; j < 6; ++j) acc[j] = (f32x4)0.0f;

    float2 areg;
    auto issueA = [&](int k0) { areg = *(const float2*)(asrc + k0); };
    auto stageB = [&](int k0, int buf) {
        // B tile 384x32 bf16 = 24 KB = 6 insts x 256 lanes x 16B, linear dest.
        // chunk c = it*256 + tid  ->  row = c>>2, k-seg = c&3
#pragma unroll
        for (int it = 0; it < 6; ++it) {
            int c = it * 256 + tid;
            __builtin_amdgcn_global_load_lds(
                (const __attribute__((address_space(1))) unsigned int*)
                    (Wb + (size_t)(c >> 2) * EMB + k0 + (c & 3) * 8),
                (__attribute__((address_space(3))) unsigned int*)
                    ((char*)&Bs[buf][0] + (it * 256 + w * 64) * 16),
                16, 0, 0);
        }
    };
    auto writeA = [&](int buf) {
        unsigned int packed = (unsigned int)f2bf(areg.x) |
                              ((unsigned int)f2bf(areg.y) << 16);
        *(unsigned int*)&As[buf][arow * PBK + ac2] = packed;
    };
    auto compute = [&](int buf) {
        short8 af = *(const short8*)&As[buf][lo * PBK + hi * 8];
#pragma unroll
        for (int j = 0; j < 6; ++j) {
            short8 bf = *(const short8*)&Bs[buf][(w * 96 + j * 16 + lo) * PBK + hi * 8];
            acc[j] = __builtin_amdgcn_mfma_f32_16x16x32_bf16(af, bf, acc[j], 0, 0, 0);
        }
    };

    // prologue
    issueA(0);            // issued FIRST: oldest vm op
    stageB(0, 0);
    writeA(0);            // compiler waits vmcnt(6) for areg
    asm volatile("s_waitcnt vmcnt(0) lgkmcnt(0)" ::: "memory");
    __builtin_amdgcn_s_barrier();

    for (int t = 0; t < PNT; ++t) {
        const int buf = t & 1;
        if (t + 1 < PNT) {
            issueA((t + 1) * PBK);
            stageB((t + 1) * PBK, buf ^ 1);
        }
        compute(buf);
        if (t + 1 < PNT) {
            writeA(buf ^ 1);                    // waits only A (vmcnt 6)
            asm volatile("s_waitcnt vmcnt(0) lgkmcnt(0)" ::: "memory");
            __builtin_amdgcn_s_barrier();
        }
    }

    // epilogue. C layout: row = hi*4+r, col = lo. cw = 16-col chunk 0..23.
    const int b = m0 >> 11;
    const int mrow0 = m0 + hi * 4;
#pragma unroll
    for (int j = 0; j < 6; ++j) {
        int cw = w * 6 + j;
        int colbase = cw * 16 + lo;
        if (cw < 8) {                      // Q
#pragma unroll
            for (int r = 0; r < 4; ++r)
                Qb[(size_t)(mrow0 + r) * HD + colbase] = f2bf(acc[j][r]);
        } else if (cw < 16) {              // K
#pragma unroll
            for (int r = 0; r < 4; ++r)
                Kb[(size_t)(mrow0 + r) * HD + (colbase - 128)] = f2bf(acc[j][r]);
        } else {                           // V -> transposed [B][HD][T]
            int h = colbase - 256;
            int tloc = mrow0 - b * T;
            ushort4 pv;
            pv.x = f2bf(acc[j][0]); pv.y = f2bf(acc[j][1]);
            pv.z = f2bf(acc[j][2]); pv.w = f2bf(acc[j][3]);
            *(ushort4*)(VtG + ((size_t)(b * HD + h)) * T + tloc) = pv;
        }
    }
}

// ---------------------------------------------------------------------------
// Kernel 2: causal flash attention with KV-split (flash-decoding style).
// ---------------------------------------------------------------------------
constexpr int QB = 64;
constexpr int KB = 64;
constexpr int STILES = 8;   // kv tiles per split block

__global__ __launch_bounds__(256) void attn_fwd(
    const unsigned short* __restrict__ Qb,
    const unsigned short* __restrict__ Kb,
    const unsigned short* __restrict__ VtG,
    float* __restrict__ out,
    float* __restrict__ part_o, float* __restrict__ part_ml,
    int use_split)
{
    const int b  = blockIdx.y;
    int bx = blockIdx.x;
    int qt, s, nsplit;
    if (use_split) {
        if (bx < 8)       { qt = bx;               s = 0; }
        else if (bx < 24) { qt = 8  + (bx - 8) / 2;  s = (bx - 8) & 1; }
        else if (bx < 48) { qt = 16 + (bx - 24) / 3; s = (bx - 24) % 3; }
        else              { qt = 24 + (bx - 48) / 4; s = (bx - 48) & 3; }
        nsplit = qt / 8 + 1;
    } else {
        qt = bx; s = 0; nsplit = 1;
    }
    const int q0 = qt * QB;
    int t0 = s * STILES;
    int t1 = t0 + STILES; if (t1 > qt + 1) t1 = qt + 1;

    const int tid  = threadIdx.x;
    const int lane = tid & 63;
    const int w    = tid >> 6;
    const int lo   = lane & 15;
    const int hi   = lane >> 4;

    __shared__ unsigned short Ks[KB][HD + 8];    // stride 272B == 4 banks mod 32
    __shared__ unsigned short Vt[HD][KB + 16];   // stride 160B == 8 banks mod 32
    __shared__ unsigned short Ps[QB][KB + 8];

    // Q fragments
    short8 qf[4];
    {
        int row = q0 + w * 16 + lo;
        const unsigned short* qp = Qb + ((size_t)b * T + row) * HD + hi * 8;
#pragma unroll
        for (int ks = 0; ks < 4; ++ks) qf[ks] = *(const short8*)(qp + ks * 32);
    }

    float mrow[4], lrow[4];
    f32x4 o[8];
#pragma unroll
    for (int r = 0; r < 4; ++r) { mrow[r] = -1e30f; lrow[r] = 0.0f; }
#pragma unroll
    for (int n = 0; n < 8; ++n) o[n] = (f32x4)0.0f;

    const float scale2 = 0.022097086912079608f * 1.4426950408889634f;
    const int qrow_base = q0 + w * 16 + hi * 4;

    for (int t = t0; t < t1; ++t) {
        const int kv0 = t * KB;
#pragma unroll
        for (int it = 0; it < 4; ++it) {
            int c = tid + it * 256;
            int row = c >> 4, c8 = (c & 15) * 8;
            *(short8*)&Ks[row][c8] =
                *(const short8*)(Kb + ((size_t)b * T + kv0 + row) * HD + c8);
        }
#pragma unroll
        for (int it = 0; it < 4; ++it) {
            int c = tid + it * 256;
            int row = c >> 3, c8 = (c & 7) * 8;
            *(short8*)&Vt[row][c8] =
                *(const short8*)(VtG + (size_t)(b * HD + row) * T + kv0 + c8);
        }
        __syncthreads();

        // S = Q K^T  (16 rows x 64 cols per wave)
        f32x4 sa[4];
#pragma unroll
        for (int j = 0; j < 4; ++j) sa[j] = (f32x4)0.0f;
#pragma unroll
        for (int ks = 0; ks < 4; ++ks) {
#pragma unroll
            for (int j = 0; j < 4; ++j) {
                short8 bf = *(const short8*)&Ks[j * 16 + lo][ks * 32 + hi * 8];
                sa[j] = __builtin_amdgcn_mfma_f32_16x16x32_bf16(qf[ks], bf, sa[j], 0, 0, 0);
            }
        }

        const bool diag = (t == qt);
        float alpha[4];
#pragma unroll
        for (int r = 0; r < 4; ++r) {
            const int qrow = qrow_base + r;
            float rm = -1e30f;
#pragma unroll
            for (int j = 0; j < 4; ++j) {
                float v = sa[j][r] * scale2;
                if (diag) {
                    int kv = kv0 + j * 16 + lo;
                    v = (kv <= qrow) ? v : -1e30f;
                }
                sa[j][r] = v;
                rm = fmaxf(rm, v);
            }
            rm = fmaxf(rm, __shfl_xor(rm, 1));
            rm = fmaxf(rm, __shfl_xor(rm, 2));
            rm = fmaxf(rm, __shfl_xor(rm, 4));
            rm = fmaxf(rm, __shfl_xor(rm, 8));
            float mn = fmaxf(mrow[r], rm);
            alpha[r] = exp2f(mrow[r] - mn);
            mrow[r] = mn;
            float ls = 0.0f;
#pragma unroll
            for (int j = 0; j < 4; ++j) {
                float p = exp2f(sa[j][r] - mn);
                sa[j][r] = p;
                ls += p;
            }
            ls += __shfl_xor(ls, 1);
            ls += __shfl_xor(ls, 2);
            ls += __shfl_xor(ls, 4);
            ls += __shfl_xor(ls, 8);
            lrow[r] = lrow[r] * alpha[r] + ls;
        }
#pragma unroll
        for (int n = 0; n < 8; ++n)
#pragma unroll
            for (int r = 0; r < 4; ++r) o[n][r] *= alpha[r];

#pragma unroll
        for (int r = 0; r < 4; ++r)
#pragma unroll
            for (int j = 0; j < 4; ++j)
                Ps[w * 16 + hi * 4 + r][j * 16 + lo] = f2bf(sa[j][r]);
        __syncthreads();

        // O += P V
#pragma unroll
        for (int ks = 0; ks < 2; ++ks) {
            short8 af = *(const short8*)&Ps[w * 16 + lo][ks * 32 + hi * 8];
#pragma unroll
            for (int n = 0; n < 8; ++n) {
                short8 bv = *(const short8*)&Vt[n * 16 + lo][ks * 32 + hi * 8];
                o[n] = __builtin_amdgcn_mfma_f32_16x16x32_bf16(af, bv, o[n], 0, 0, 0);
            }
        }
        __syncthreads();
    }

    if (nsplit == 1) {
#pragma unroll
        for (int n = 0; n < 8; ++n) {
            int h = n * 16 + lo;
#pragma unroll
            for (int r = 0; r < 4; ++r) {
                int row = qrow_base + r;
                out[((size_t)b * T + row) * HD + h] = o[n][r] / lrow[r];
            }
        }
    } else {
        const size_t slot = (size_t)(b * 32 + qt) * 4 + s;
        float* po = part_o + slot * (QB * HD);
#pragma unroll
        for (int n = 0; n < 8; ++n) {
            int h = n * 16 + lo;
#pragma unroll
            for (int r = 0; r < 4; ++r)
                po[(w * 16 + hi * 4 + r) * HD + h] = o[n][r];
        }
        if (lo == 0) {
            float* pm = part_ml + slot * (QB * 2);
#pragma unroll
            for (int r = 0; r < 4; ++r) {
                pm[(w * 16 + hi * 4 + r) * 2 + 0] = mrow[r];
                pm[(w * 16 + hi * 4 + r) * 2 + 1] = lrow[r];
            }
        }
    }
}

// ---------------------------------------------------------------------------
// Kernel 3: combine split partials (only q-tiles 8..31 have >1 split)
// ---------------------------------------------------------------------------
__global__ __launch_bounds__(256) void attn_combine(
    const float* __restrict__ part_o, const float* __restrict__ part_ml,
    float* __restrict__ out)
{
    const int qt = 8 + blockIdx.x;     // 8..31
    const int b  = blockIdx.y;
    const int ns = qt / 8 + 1;         // 2..4
    const int tid = threadIdx.x;
    const int row = tid >> 2;          // 0..63
    const int c0  = (tid & 3) * 32;
    const size_t slot0 = (size_t)(b * 32 + qt) * 4;

    float mi[4], li[4];
    float m = -1e30f;
#pragma unroll 4
    for (int i = 0; i < ns; ++i) {
        mi[i] = part_ml[(slot0 + i) * (QB * 2) + row * 2 + 0];
        li[i] = part_ml[(slot0 + i) * (QB * 2) + row * 2 + 1];
        m = fmaxf(m, mi[i]);
    }
    float L = 0.0f, f[4];
#pragma unroll 4
    for (int i = 0; i < ns; ++i) {
        f[i] = exp2f(mi[i] - m);
        L += li[i] * f[i];
    }
    const float inv = 1.0f / L;

    float4 acc[8];
#pragma unroll
    for (int k = 0; k < 8; ++k) acc[k] = make_float4(0.f, 0.f, 0.f, 0.f);
#pragma unroll 4
    for (int i = 0; i < ns; ++i) {
        const float4* src = (const float4*)(part_o + (slot0 + i) * (QB * HD) + row * HD + c0);
#pragma unroll
        for (int k = 0; k < 8; ++k) {
            float4 v = src[k];
            acc[k].x += f[i] * v.x; acc[k].y += f[i] * v.y;
            acc[k].z += f[i] * v.z; acc[k].w += f[i] * v.w;
        }
    }
    float4* dst = (float4*)(out + ((size_t)b * T + qt * QB + row) * HD + c0);
#pragma unroll
    for (int k = 0; k < 8; ++k) {
        float4 v = acc[k];
        dst[k] = make_float4(v.x * inv, v.y * inv, v.z * inv, v.w * inv);
    }
}

// ---------------------------------------------------------------------------
extern "C" void kernel_launch(void* const* d_in, const int* in_sizes, int n_in,
                              void* d_out, int out_size, void* d_ws, size_t ws_size,
                              hipStream_t stream)
{
    const float* x  = (const float*)d_in[0];
    const float* Wq = (const float*)d_in[1];
    const float* Wk = (const float*)d_in[2];
    const float* Wv = (const float*)d_in[3];
    float* out = (float*)d_out;

    // ws layout (bytes)
    const size_t off_Wb = 0;
    const size_t off_Q  = off_Wb + (size_t)NW * EMB * 2;        // 1.5 MB
    const size_t off_K  = off_Q  + (size_t)M * HD * 2;          // +4 MB
    const size_t off_V  = off_K  + (size_t)M * HD * 2;
    const size_t off_po = off_V  + (size_t)M * HD * 2;
    const size_t off_ml = off_po + (size_t)1024 * QB * HD * 4;  // 32 MB partials
    const size_t total  = off_ml + (size_t)1024 * QB * 2 * 4;

    char* ws = (char*)d_ws;
    unsigned short* Wb  = (unsigned short*)(ws + off_Wb);
    unsigned short* Qb  = (unsigned short*)(ws + off_Q);
    unsigned short* Kb  = (unsigned short*)(ws + off_K);
    unsigned short* VtG = (unsigned short*)(ws + off_V);
    float* part_o  = (float*)(ws + off_po);
    float* part_ml = (float*)(ws + off_ml);

    const int use_split = (ws_size >= total) ? 1 : 0;

    conv_w<<<dim3((NW * EMB) / (256 * 8)), 256, 0, stream>>>(Wq, Wk, Wv, Wb);
    qkv_proj<<<dim3(M / PBM), 256, 0, stream>>>(x, Wb, Qb, Kb, VtG);
    attn_fwd<<<dim3(use_split ? 80 : 32, B), 256, 0, stream>>>(
        Qb, Kb, VtG, out, part_o, part_ml, use_split);
    if (use_split)
        attn_combine<<<dim3(24, B), 256, 0, stream>>>(part_o, part_ml, out);
}

// Round 6
// 160.282 us; speedup vs baseline: 1.2275x; 1.2275x over previous
//
#include <hip/hip_runtime.h>
#include <hip/hip_bf16.h>
#include <stdint.h>

// Problem constants
constexpr int B    = 8;
constexpr int T    = 2048;
constexpr int EMB  = 2048;
constexpr int HD   = 128;
constexpr int M    = B * T;        // 16384 rows for projection GEMM
constexpr int NW   = 3 * HD;       // 384 fused output cols (Q|K|V)

typedef __attribute__((ext_vector_type(8))) short short8;
typedef __attribute__((ext_vector_type(4))) float f32x4;

__device__ inline unsigned short f2bf(float f) {
    union { float f; unsigned int u; } v; v.f = f;
    unsigned int x = v.u;
    unsigned int r = (x + 0x7FFFu + ((x >> 16) & 1u)) >> 16;   // RNE
    return (unsigned short)r;
}

__device__ inline unsigned int cvt_pk_bf16(float a, float b) {
    unsigned int r;
    asm volatile("v_cvt_pk_bf16_f32 %0, %1, %2" : "=v"(r) : "v"(a), "v"(b));
    return r;   // lo = bf16(a), hi = bf16(b), RNE
}

// ---------------------------------------------------------------------------
// Kernel 0: convert Wq|Wk|Wv fp32 -> bf16 into Wb[384][2048]
// ---------------------------------------------------------------------------
__global__ __launch_bounds__(256) void conv_w(
    const float* __restrict__ Wq, const float* __restrict__ Wk, const float* __restrict__ Wv,
    unsigned short* __restrict__ Wb)
{
    int base = (blockIdx.x * 256 + threadIdx.x) * 8;   // < 384*2048
    int row = base >> 11, col = base & 2047;
    const float* src;
    if (row < 128)      src = Wq + (size_t)row * EMB + col;
    else if (row < 256) src = Wk + (size_t)(row - 128) * EMB + col;
    else                src = Wv + (size_t)(row - 256) * EMB + col;
    float4 a = *(const float4*)src;
    float4 b = *(const float4*)(src + 4);
    short8 sv;
    sv[0] = f2bf(a.x); sv[1] = f2bf(a.y); sv[2] = f2bf(a.z); sv[3] = f2bf(a.w);
    sv[4] = f2bf(b.x); sv[5] = f2bf(b.y); sv[6] = f2bf(b.z); sv[7] = f2bf(b.w);
    *(short8*)(Wb + base) = sv;
}

// ---------------------------------------------------------------------------
// Kernel 1: QKV projection, m97-structure GEMM.
// Tile 128(M) x 128(N), BK=64, 32 K-steps. Grid 384 = 128 M-tiles x 3 N-tiles
// (nt: 0=Q 1=K 2=V), all co-resident (2 blocks/CU, LDS 64 KB). 256 thr =
// 4 waves (2x2), wave = 64x64 = 4x4 16x16 frags: 8 ds_read_b128 per 16 MFMA.
// B (Wb bf16): global_load_lds, source-side XOR swizzle (c16 ^= row&7).
// A (x fp32): reg-staged, v_cvt_pk_bf16_f32, ds_write XOR-swizzled.
// XCD mapping: the 3 N-twins of an M-tile land on the same XCD (share x in L2).
// Q,K written [M][128] bf16; V written TRANSPOSED [B][128][T] bf16.
// ---------------------------------------------------------------------------
constexpr int GBM = 128;
constexpr int GBK = 64;
constexpr int GNT = EMB / GBK;   // 32

__global__ __launch_bounds__(256) void qkv_proj(
    const float* __restrict__ x, const unsigned short* __restrict__ Wb,
    unsigned short* __restrict__ Qb, unsigned short* __restrict__ Kb,
    unsigned short* __restrict__ VtG)
{
    __shared__ unsigned short As[2][GBM * GBK];   // 2 x 16 KB
    __shared__ unsigned short Bs[2][GBM * GBK];   // 2 x 16 KB

    // block mapping: d -> (mt, nt), N-twins of an M-tile share an XCD (d&7)
    const int d  = blockIdx.x;          // 0..383
    const int Xc = d & 7;
    const int i0 = d >> 3;              // 0..47
    const int mt = (i0 / 3) * 8 + Xc;   // 0..127
    const int nt = i0 % 3;              // 0..2
    const int m0 = mt * GBM;
    const int nrow0 = nt * 128;         // row offset into Wb

    const int tid  = threadIdx.x;
    const int lane = tid & 63;
    const int w    = tid >> 6;
    const int wr   = w >> 1;            // 0..1
    const int wc   = w & 1;             // 0..1
    const int lo   = lane & 15;
    const int hi   = lane >> 4;
    const int lx   = lo & 7;

    // A staging: thread covers half a row (32 floats)
    const int arow  = tid >> 1;              // 0..127
    const int ahalf = (tid & 1) * 32;
    const float* asrc = x + (size_t)(m0 + arow) * EMB + ahalf;

    f32x4 acc[4][4];
#pragma unroll
    for (int i = 0; i < 4; ++i)
#pragma unroll
        for (int j = 0; j < 4; ++j) acc[i][j] = (f32x4)0.0f;

    float4 areg[8];

    auto issueA = [&](int k0) {
#pragma unroll
        for (int q = 0; q < 8; ++q)
            areg[q] = *(const float4*)(asrc + k0 + q * 4);
    };
    auto stageB = [&](int k0, int buf) {
        // 128x64 bf16 = 16 KB = 1024 x 16B chunks; 4 insts x 256 lanes.
        // chunk idx = it*256 + tid -> row = idx>>3, phys c16 = idx&7,
        // logical c16 = phys ^ (row&7)  (source pre-swizzle, dest linear)
#pragma unroll
        for (int it = 0; it < 4; ++it) {
            int idx = it * 256 + tid;
            int row = idx >> 3;
            int lc  = (idx & 7) ^ (row & 7);
            __builtin_amdgcn_global_load_lds(
                (const __attribute__((address_space(1))) unsigned int*)
                    (Wb + (size_t)(nrow0 + row) * EMB + k0 + lc * 8),
                (__attribute__((address_space(3))) unsigned int*)
                    ((char*)&Bs[buf][0] + (it * 256 + w * 64) * 16),
                16, 0, 0);
        }
    };
    auto writeA = [&](int buf) {
        const int rx = arow & 7;
#pragma unroll
        for (int j2 = 0; j2 < 4; ++j2) {
            float4 u = areg[j2 * 2], v = areg[j2 * 2 + 1];
            uint4 p;
            p.x = cvt_pk_bf16(u.x, u.y);
            p.y = cvt_pk_bf16(u.z, u.w);
            p.z = cvt_pk_bf16(v.x, v.y);
            p.w = cvt_pk_bf16(v.z, v.w);
            int c16 = (((tid & 1) * 4) + j2) ^ rx;
            *(uint4*)&As[buf][arow * GBK + c16 * 8] = p;
        }
    };
    auto compute = [&](int buf) {
#pragma unroll
        for (int kk = 0; kk < 2; ++kk) {
            short8 af[4], bfr[4];
            const int c16 = (kk * 4 + hi) ^ lx;
#pragma unroll
            for (int i = 0; i < 4; ++i)
                af[i] = *(const short8*)&As[buf][(wr * 64 + i * 16 + lo) * GBK + c16 * 8];
#pragma unroll
            for (int j = 0; j < 4; ++j)
                bfr[j] = *(const short8*)&Bs[buf][(wc * 64 + j * 16 + lo) * GBK + c16 * 8];
#pragma unroll
            for (int i = 0; i < 4; ++i)
#pragma unroll
                for (int j = 0; j < 4; ++j)
                    acc[i][j] = __builtin_amdgcn_mfma_f32_16x16x32_bf16(af[i], bfr[j], acc[i][j], 0, 0, 0);
        }
    };

    // prologue
    issueA(0);
    stageB(0, 0);
    writeA(0);
    asm volatile("s_waitcnt vmcnt(0) lgkmcnt(0)" ::: "memory");
    __builtin_amdgcn_s_barrier();

    for (int t = 0; t < GNT; ++t) {
        const int buf = t & 1;
        if (t + 1 < GNT) {
            issueA((t + 1) * GBK);
            stageB((t + 1) * GBK, buf ^ 1);
        }
        compute(buf);
        if (t + 1 < GNT) {
            writeA(buf ^ 1);
            asm volatile("s_waitcnt vmcnt(0) lgkmcnt(0)" ::: "memory");
            __builtin_amdgcn_s_barrier();
        }
    }

    // epilogue. C layout: row = hi*4+r, col = lo.
    const int b = m0 >> 11;
#pragma unroll
    for (int i = 0; i < 4; ++i) {
        int mrow0 = m0 + wr * 64 + i * 16 + hi * 4;
#pragma unroll
        for (int j = 0; j < 4; ++j) {
            int col = wc * 64 + j * 16 + lo;   // 0..127 = head dim
            if (nt == 0) {                     // Q
#pragma unroll
                for (int r = 0; r < 4; ++r)
                    Qb[(size_t)(mrow0 + r) * HD + col] = f2bf(acc[i][j][r]);
            } else if (nt == 1) {              // K
#pragma unroll
                for (int r = 0; r < 4; ++r)
                    Kb[(size_t)(mrow0 + r) * HD + col] = f2bf(acc[i][j][r]);
            } else {                           // V -> transposed [B][HD][T]
                int tloc = mrow0 - b * T;
                ushort4 pv;
                pv.x = f2bf(acc[i][j][0]); pv.y = f2bf(acc[i][j][1]);
                pv.z = f2bf(acc[i][j][2]); pv.w = f2bf(acc[i][j][3]);
                *(ushort4*)(VtG + ((size_t)(b * HD + col)) * T + tloc) = pv;
            }
        }
    }
}

// ---------------------------------------------------------------------------
// Kernel 2: causal flash attention with KV-split (flash-decoding style).
// ---------------------------------------------------------------------------
constexpr int QB = 64;
constexpr int KB = 64;
constexpr int STILES = 8;   // kv tiles per split block

__global__ __launch_bounds__(256) void attn_fwd(
    const unsigned short* __restrict__ Qb,
    const unsigned short* __restrict__ Kb,
    const unsigned short* __restrict__ VtG,
    float* __restrict__ out,
    float* __restrict__ part_o, float* __restrict__ part_ml,
    int use_split)
{
    const int b  = blockIdx.y;
    int bx = blockIdx.x;
    int qt, s, nsplit;
    if (use_split) {
        if (bx < 8)       { qt = bx;               s = 0; }
        else if (bx < 24) { qt = 8  + (bx - 8) / 2;  s = (bx - 8) & 1; }
        else if (bx < 48) { qt = 16 + (bx - 24) / 3; s = (bx - 24) % 3; }
        else              { qt = 24 + (bx - 48) / 4; s = (bx - 48) & 3; }
        nsplit = qt / 8 + 1;
    } else {
        qt = bx; s = 0; nsplit = 1;
    }
    const int q0 = qt * QB;
    int t0 = s * STILES;
    int t1 = t0 + STILES; if (t1 > qt + 1) t1 = qt + 1;

    const int tid  = threadIdx.x;
    const int lane = tid & 63;
    const int w    = tid >> 6;
    const int lo   = lane & 15;
    const int hi   = lane >> 4;

    __shared__ unsigned short Ks[KB][HD + 8];    // stride 272B == 4 banks mod 32
    __shared__ unsigned short Vt[HD][KB + 16];   // stride 160B == 8 banks mod 32
    __shared__ unsigned short Ps[QB][KB + 8];

    // Q fragments
    short8 qf[4];
    {
        int row = q0 + w * 16 + lo;
        const unsigned short* qp = Qb + ((size_t)b * T + row) * HD + hi * 8;
#pragma unroll
        for (int ks = 0; ks < 4; ++ks) qf[ks] = *(const short8*)(qp + ks * 32);
    }

    float mrow[4], lrow[4];
    f32x4 o[8];
#pragma unroll
    for (int r = 0; r < 4; ++r) { mrow[r] = -1e30f; lrow[r] = 0.0f; }
#pragma unroll
    for (int n = 0; n < 8; ++n) o[n] = (f32x4)0.0f;

    const float scale2 = 0.022097086912079608f * 1.4426950408889634f;
    const int qrow_base = q0 + w * 16 + hi * 4;

    for (int t = t0; t < t1; ++t) {
        const int kv0 = t * KB;
#pragma unroll
        for (int it = 0; it < 4; ++it) {
            int c = tid + it * 256;
            int row = c >> 4, c8 = (c & 15) * 8;
            *(short8*)&Ks[row][c8] =
                *(const short8*)(Kb + ((size_t)b * T + kv0 + row) * HD + c8);
        }
#pragma unroll
        for (int it = 0; it < 4; ++it) {
            int c = tid + it * 256;
            int row = c >> 3, c8 = (c & 7) * 8;
            *(short8*)&Vt[row][c8] =
                *(const short8*)(VtG + (size_t)(b * HD + row) * T + kv0 + c8);
        }
        __syncthreads();

        // S = Q K^T  (16 rows x 64 cols per wave)
        f32x4 sa[4];
#pragma unroll
        for (int j = 0; j < 4; ++j) sa[j] = (f32x4)0.0f;
#pragma unroll
        for (int ks = 0; ks < 4; ++ks) {
#pragma unroll
            for (int j = 0; j < 4; ++j) {
                short8 bf = *(const short8*)&Ks[j * 16 + lo][ks * 32 + hi * 8];
                sa[j] = __builtin_amdgcn_mfma_f32_16x16x32_bf16(qf[ks], bf, sa[j], 0, 0, 0);
            }
        }

        const bool diag = (t == qt);
        float alpha[4];
#pragma unroll
        for (int r = 0; r < 4; ++r) {
            const int qrow = qrow_base + r;
            float rm = -1e30f;
#pragma unroll
            for (int j = 0; j < 4; ++j) {
                float v = sa[j][r] * scale2;
                if (diag) {
                    int kv = kv0 + j * 16 + lo;
                    v = (kv <= qrow) ? v : -1e30f;
                }
                sa[j][r] = v;
                rm = fmaxf(rm, v);
            }
            rm = fmaxf(rm, __shfl_xor(rm, 1));
            rm = fmaxf(rm, __shfl_xor(rm, 2));
            rm = fmaxf(rm, __shfl_xor(rm, 4));
            rm = fmaxf(rm, __shfl_xor(rm, 8));
            float mn = fmaxf(mrow[r], rm);
            alpha[r] = exp2f(mrow[r] - mn);
            mrow[r] = mn;
            float ls = 0.0f;
#pragma unroll
            for (int j = 0; j < 4; ++j) {
                float p = exp2f(sa[j][r] - mn);
                sa[j][r] = p;
                ls += p;
            }
            ls += __shfl_xor(ls, 1);
            ls += __shfl_xor(ls, 2);
            ls += __shfl_xor(ls, 4);
            ls += __shfl_xor(ls, 8);
            lrow[r] = lrow[r] * alpha[r] + ls;
        }
#pragma unroll
        for (int n = 0; n < 8; ++n)
#pragma unroll
            for (int r = 0; r < 4; ++r) o[n][r] *= alpha[r];

#pragma unroll
        for (int r = 0; r < 4; ++r)
#pragma unroll
            for (int j = 0; j < 4; ++j)
                Ps[w * 16 + hi * 4 + r][j * 16 + lo] = f2bf(sa[j][r]);
        __syncthreads();

        // O += P V
#pragma unroll
        for (int ks = 0; ks < 2; ++ks) {
            short8 af = *(const short8*)&Ps[w * 16 + lo][ks * 32 + hi * 8];
#pragma unroll
            for (int n = 0; n < 8; ++n) {
                short8 bv = *(const short8*)&Vt[n * 16 + lo][ks * 32 + hi * 8];
                o[n] = __builtin_amdgcn_mfma_f32_16x16x32_bf16(af, bv, o[n], 0, 0, 0);
            }
        }
        __syncthreads();
    }

    if (nsplit == 1) {
#pragma unroll
        for (int n = 0; n < 8; ++n) {
            int h = n * 16 + lo;
#pragma unroll
            for (int r = 0; r < 4; ++r) {
                int row = qrow_base + r;
                out[((size_t)b * T + row) * HD + h] = o[n][r] / lrow[r];
            }
        }
    } else {
        const size_t slot = (size_t)(b * 32 + qt) * 4 + s;
        float* po = part_o + slot * (QB * HD);
#pragma unroll
        for (int n = 0; n < 8; ++n) {
            int h = n * 16 + lo;
#pragma unroll
            for (int r = 0; r < 4; ++r)
                po[(w * 16 + hi * 4 + r) * HD + h] = o[n][r];
        }
        if (lo == 0) {
            float* pm = part_ml + slot * (QB * 2);
#pragma unroll
            for (int r = 0; r < 4; ++r) {
                pm[(w * 16 + hi * 4 + r) * 2 + 0] = mrow[r];
                pm[(w * 16 + hi * 4 + r) * 2 + 1] = lrow[r];
            }
        }
    }
}

// ---------------------------------------------------------------------------
// Kernel 3: combine split partials (only q-tiles 8..31 have >1 split)
// ---------------------------------------------------------------------------
__global__ __launch_bounds__(256) void attn_combine(
    const float* __restrict__ part_o, const float* __restrict__ part_ml,
    float* __restrict__ out)
{
    const int qt = 8 + blockIdx.x;     // 8..31
    const int b  = blockIdx.y;
    const int ns = qt / 8 + 1;         // 2..4
    const int tid = threadIdx.x;
    const int row = tid >> 2;          // 0..63
    const int c0  = (tid & 3) * 32;
    const size_t slot0 = (size_t)(b * 32 + qt) * 4;

    float mi[4], li[4];
    float m = -1e30f;
#pragma unroll 4
    for (int i = 0; i < ns; ++i) {
        mi[i] = part_ml[(slot0 + i) * (QB * 2) + row * 2 + 0];
        li[i] = part_ml[(slot0 + i) * (QB * 2) + row * 2 + 1];
        m = fmaxf(m, mi[i]);
    }
    float L = 0.0f, f[4];
#pragma unroll 4
    for (int i = 0; i < ns; ++i) {
        f[i] = exp2f(mi[i] - m);
        L += li[i] * f[i];
    }
    const float inv = 1.0f / L;

    float4 acc[8];
#pragma unroll
    for (int k = 0; k < 8; ++k) acc[k] = make_float4(0.f, 0.f, 0.f, 0.f);
#pragma unroll 4
    for (int i = 0; i < ns; ++i) {
        const float4* src = (const float4*)(part_o + (slot0 + i) * (QB * HD) + row * HD + c0);
#pragma unroll
        for (int k = 0; k < 8; ++k) {
            float4 v = src[k];
            acc[k].x += f[i] * v.x; acc[k].y += f[i] * v.y;
            acc[k].z += f[i] * v.z; acc[k].w += f[i] * v.w;
        }
    }
    float4* dst = (float4*)(out + ((size_t)b * T + qt * QB + row) * HD + c0);
#pragma unroll
    for (int k = 0; k < 8; ++k) {
        float4 v = acc[k];
        dst[k] = make_float4(v.x * inv, v.y * inv, v.z * inv, v.w * inv);
    }
}

// ---------------------------------------------------------------------------
extern "C" void kernel_launch(void* const* d_in, const int* in_sizes, int n_in,
                              void* d_out, int out_size, void* d_ws, size_t ws_size,
                              hipStream_t stream)
{
    const float* x  = (const float*)d_in[0];
    const float* Wq = (const float*)d_in[1];
    const float* Wk = (const float*)d_in[2];
    const float* Wv = (const float*)d_in[3];
    float* out = (float*)d_out;

    // ws layout (bytes)
    const size_t off_Wb = 0;
    const size_t off_Q  = off_Wb + (size_t)NW * EMB * 2;        // 1.5 MB
    const size_t off_K  = off_Q  + (size_t)M * HD * 2;          // +4 MB
    const size_t off_V  = off_K  + (size_t)M * HD * 2;
    const size_t off_po = off_V  + (size_t)M * HD * 2;
    const size_t off_ml = off_po + (size_t)1024 * QB * HD * 4;  // 32 MB partials
    const size_t total  = off_ml + (size_t)1024 * QB * 2 * 4;

    char* ws = (char*)d_ws;
    unsigned short* Wb  = (unsigned short*)(ws + off_Wb);
    unsigned short* Qb  = (unsigned short*)(ws + off_Q);
    unsigned short* Kb  = (unsigned short*)(ws + off_K);
    unsigned short* VtG = (unsigned short*)(ws + off_V);
    float* part_o  = (float*)(ws + off_po);
    float* part_ml = (float*)(ws + off_ml);

    const int use_split = (ws_size >= total) ? 1 : 0;

    conv_w<<<dim3((NW * EMB) / (256 * 8)), 256, 0, stream>>>(Wq, Wk, Wv, Wb);
    qkv_proj<<<dim3(384), 256, 0, stream>>>(x, Wb, Qb, Kb, VtG);
    attn_fwd<<<dim3(use_split ? 80 : 32, B), 256, 0, stream>>>(
        Qb, Kb, VtG, out, part_o, part_ml, use_split);
    if (use_split)
        attn_combine<<<dim3(24, B), 256, 0, stream>>>(part_o, part_ml, out);
}

// Round 7
// 113.349 us; speedup vs baseline: 1.7357x; 1.4141x over previous
//
#include <hip/hip_runtime.h>
#include <hip/hip_bf16.h>
#include <stdint.h>

// Problem constants
constexpr int B    = 8;
constexpr int T    = 2048;
constexpr int EMB  = 2048;
constexpr int HD   = 128;
constexpr int M    = B * T;        // 16384 rows for projection GEMM
constexpr int NW   = 3 * HD;       // 384 fused output cols (Q|K|V)

typedef __attribute__((ext_vector_type(8))) short short8;
typedef __attribute__((ext_vector_type(4))) float f32x4;

__device__ inline unsigned short f2bf(float f) {
    union { float f; unsigned int u; } v; v.f = f;
    unsigned int x = v.u;
    unsigned int r = (x + 0x7FFFu + ((x >> 16) & 1u)) >> 16;   // RNE
    return (unsigned short)r;
}

__device__ inline unsigned int cvt_pk_bf16(float a, float b) {
    unsigned int r;
    asm volatile("v_cvt_pk_bf16_f32 %0, %1, %2" : "=v"(r) : "v"(a), "v"(b));
    return r;   // lo = bf16(a), hi = bf16(b)
}

// ---------------------------------------------------------------------------
// Kernel 0: convert Wq|Wk|Wv fp32 -> bf16 into Wb[384][2048]
// ---------------------------------------------------------------------------
__global__ __launch_bounds__(256) void conv_w(
    const float* __restrict__ Wq, const float* __restrict__ Wk, const float* __restrict__ Wv,
    unsigned short* __restrict__ Wb)
{
    int base = (blockIdx.x * 256 + threadIdx.x) * 8;   // < 384*2048
    int row = base >> 11, col = base & 2047;
    const float* src;
    if (row < 128)      src = Wq + (size_t)row * EMB + col;
    else if (row < 256) src = Wk + (size_t)(row - 128) * EMB + col;
    else                src = Wv + (size_t)(row - 256) * EMB + col;
    float4 a = *(const float4*)src;
    float4 b = *(const float4*)(src + 4);
    short8 sv;
    sv[0] = f2bf(a.x); sv[1] = f2bf(a.y); sv[2] = f2bf(a.z); sv[3] = f2bf(a.w);
    sv[4] = f2bf(b.x); sv[5] = f2bf(b.y); sv[6] = f2bf(b.z); sv[7] = f2bf(b.w);
    *(short8*)(Wb + base) = sv;
}

// ---------------------------------------------------------------------------
// Kernel 1: fused QKV projection.
// Tile 32(M) x 384(N=full, x read ONCE) x BK=64, 32 K-steps. Grid 512 ->
// 2 blocks/CU (LDS 56 KB). 256 thr = 4 waves; wave w = cols w*96..+95, all
// 32 rows: 2x6 16x16 frags, 24 MFMA / 16 ds_read_b128 per step.
// B (Wb bf16, L2-resident): global_load_lds single-buffer, restaged per step
//   post-barrier (~300cy L2 latency exposed, hidden by twin block).
// A (x fp32): reg-prefetched one step early, cvt_pk at write, double-buffered.
// LDS swizzle: 16B-chunk XOR by (row&7), same involution on write+read (G4/m214).
// Q,K written [M][128] bf16; V written TRANSPOSED [B][128][T] bf16.
// ---------------------------------------------------------------------------
constexpr int PBM = 32;
constexpr int PBK = 64;
constexpr int PNT = EMB / PBK;   // 32

__global__ __launch_bounds__(256) void qkv_proj(
    const float* __restrict__ x, const unsigned short* __restrict__ Wb,
    unsigned short* __restrict__ Qb, unsigned short* __restrict__ Kb,
    unsigned short* __restrict__ VtG)
{
    __shared__ unsigned short Asm[2][PBM * PBK];   // 2 x 4 KB
    __shared__ unsigned short Bsm[NW * PBK];       // 48 KB single buffer

    const int m0   = blockIdx.x * PBM;
    const int tid  = threadIdx.x;
    const int lane = tid & 63;
    const int w    = tid >> 6;           // 0..3
    const int lo   = lane & 15;
    const int hi   = lane >> 4;

    // A staging: thread -> (row ar, 8-float seg as); coalesced 256B per 8 lanes
    const int ar = tid >> 3;             // 0..31
    const int as = tid & 7;              // 0..7
    const float* asrc = x + (size_t)(m0 + ar) * EMB + as * 8;

    f32x4 acc[2][6];
#pragma unroll
    for (int i = 0; i < 2; ++i)
#pragma unroll
        for (int j = 0; j < 6; ++j) acc[i][j] = (f32x4)0.0f;

    float4 a0, a1;
    auto issueA = [&](int k0) {
        a0 = *(const float4*)(asrc + k0);
        a1 = *(const float4*)(asrc + k0 + 4);
    };
    auto writeA = [&](int buf) {
        uint4 p;
        p.x = cvt_pk_bf16(a0.x, a0.y);
        p.y = cvt_pk_bf16(a0.z, a0.w);
        p.z = cvt_pk_bf16(a1.x, a1.y);
        p.w = cvt_pk_bf16(a1.z, a1.w);
        int ps = as ^ (ar & 7);                       // chunk XOR by row
        *(uint4*)&Asm[buf][ar * PBK + ps * 8] = p;
    };
    auto stageB = [&](int k0) {
        // 384x64 bf16 = 48 KB = 3072 x 16B chunks = 12 insts x 256 lanes.
        // phys chunk c = it*256+tid -> row=c>>3, pseg=c&7; logical seg = pseg^(row&7)
#pragma unroll
        for (int it = 0; it < 12; ++it) {
            int c = it * 256 + tid;
            int row = c >> 3;
            int lseg = (c & 7) ^ (row & 7);
            __builtin_amdgcn_global_load_lds(
                (const __attribute__((address_space(1))) unsigned int*)
                    (Wb + (size_t)row * EMB + k0 + lseg * 8),
                (__attribute__((address_space(3))) unsigned int*)
                    ((char*)&Bsm[0] + (it * 256 + w * 64) * 16),
                16, 0, 0);
        }
    };
    auto compute = [&](int buf) {
#pragma unroll
        for (int kk = 0; kk < 2; ++kk) {
            short8 af[2], bf[6];
#pragma unroll
            for (int i = 0; i < 2; ++i) {
                int R = i * 16 + lo;
                int pseg = (kk * 4 + hi) ^ (R & 7);
                af[i] = *(const short8*)&Asm[buf][R * PBK + pseg * 8];
            }
#pragma unroll
            for (int j = 0; j < 6; ++j) {
                int n = w * 96 + j * 16 + lo;
                int pseg = (kk * 4 + hi) ^ (n & 7);
                bf[j] = *(const short8*)&Bsm[n * PBK + pseg * 8];
            }
#pragma unroll
            for (int i = 0; i < 2; ++i)
#pragma unroll
                for (int j = 0; j < 6; ++j)
                    acc[i][j] = __builtin_amdgcn_mfma_f32_16x16x32_bf16(af[i], bf[j], acc[i][j], 0, 0, 0);
        }
    };

    // prologue: A(0) regs -> LDS[0]; B(0) DMA; drain; barrier
    issueA(0);
    stageB(0);
    writeA(0);
    asm volatile("s_waitcnt vmcnt(0) lgkmcnt(0)" ::: "memory");
    __builtin_amdgcn_s_barrier();

    int cur = 0;
    for (int t = 0; t < PNT; ++t) {
        if (t + 1 < PNT) issueA((t + 1) * PBK);   // x latency hides under compute
        compute(cur);
        __builtin_amdgcn_s_barrier();             // all waves done reading B(t), A[cur]
        if (t + 1 < PNT) {
            stageB((t + 1) * PBK);                // overwrite B (L2-resident, ~short)
            writeA(cur ^ 1);
            asm volatile("s_waitcnt vmcnt(0) lgkmcnt(0)" ::: "memory");
            __builtin_amdgcn_s_barrier();
        }
        cur ^= 1;
    }

    // epilogue. C layout: row = hi*4+r, col = lo. cw = 16-col chunk 0..23.
    const int b = m0 >> 11;
#pragma unroll
    for (int i = 0; i < 2; ++i) {
        int mrow0 = m0 + i * 16 + hi * 4;
#pragma unroll
        for (int j = 0; j < 6; ++j) {
            int cw = w * 6 + j;
            int colbase = cw * 16 + lo;
            if (cw < 8) {                      // Q
#pragma unroll
                for (int r = 0; r < 4; ++r)
                    Qb[(size_t)(mrow0 + r) * HD + colbase] = f2bf(acc[i][j][r]);
            } else if (cw < 16) {              // K
#pragma unroll
                for (int r = 0; r < 4; ++r)
                    Kb[(size_t)(mrow0 + r) * HD + (colbase - 128)] = f2bf(acc[i][j][r]);
            } else {                           // V -> transposed [B][HD][T]
                int h = colbase - 256;
                int tloc = mrow0 - b * T;
                ushort4 pv;
                pv.x = f2bf(acc[i][j][0]); pv.y = f2bf(acc[i][j][1]);
                pv.z = f2bf(acc[i][j][2]); pv.w = f2bf(acc[i][j][3]);
                *(ushort4*)(VtG + ((size_t)(b * HD + h)) * T + tloc) = pv;
            }
        }
    }
}

// ---------------------------------------------------------------------------
// Kernel 2: causal flash attention with KV-split (flash-decoding style).
// ---------------------------------------------------------------------------
constexpr int QB = 64;
constexpr int KB = 64;
constexpr int STILES = 8;   // kv tiles per split block

__global__ __launch_bounds__(256) void attn_fwd(
    const unsigned short* __restrict__ Qb,
    const unsigned short* __restrict__ Kb,
    const unsigned short* __restrict__ VtG,
    float* __restrict__ out,
    float* __restrict__ part_o, float* __restrict__ part_ml,
    int use_split)
{
    const int b  = blockIdx.y;
    int bx = blockIdx.x;
    int qt, s, nsplit;
    if (use_split) {
        if (bx < 8)       { qt = bx;               s = 0; }
        else if (bx < 24) { qt = 8  + (bx - 8) / 2;  s = (bx - 8) & 1; }
        else if (bx < 48) { qt = 16 + (bx - 24) / 3; s = (bx - 24) % 3; }
        else              { qt = 24 + (bx - 48) / 4; s = (bx - 48) & 3; }
        nsplit = qt / 8 + 1;
    } else {
        qt = bx; s = 0; nsplit = 1;
    }
    const int q0 = qt * QB;
    int t0 = s * STILES;
    int t1 = t0 + STILES; if (t1 > qt + 1) t1 = qt + 1;

    const int tid  = threadIdx.x;
    const int lane = tid & 63;
    const int w    = tid >> 6;
    const int lo   = lane & 15;
    const int hi   = lane >> 4;

    __shared__ unsigned short Ks[KB][HD + 8];    // stride 272B == 4 banks mod 32
    __shared__ unsigned short Vt[HD][KB + 16];   // stride 160B == 8 banks mod 32
    __shared__ unsigned short Ps[QB][KB + 8];

    // Q fragments
    short8 qf[4];
    {
        int row = q0 + w * 16 + lo;
        const unsigned short* qp = Qb + ((size_t)b * T + row) * HD + hi * 8;
#pragma unroll
        for (int ks = 0; ks < 4; ++ks) qf[ks] = *(const short8*)(qp + ks * 32);
    }

    float mrow[4], lrow[4];
    f32x4 o[8];
#pragma unroll
    for (int r = 0; r < 4; ++r) { mrow[r] = -1e30f; lrow[r] = 0.0f; }
#pragma unroll
    for (int n = 0; n < 8; ++n) o[n] = (f32x4)0.0f;

    const float scale2 = 0.022097086912079608f * 1.4426950408889634f;
    const int qrow_base = q0 + w * 16 + hi * 4;

    for (int t = t0; t < t1; ++t) {
        const int kv0 = t * KB;
#pragma unroll
        for (int it = 0; it < 4; ++it) {
            int c = tid + it * 256;
            int row = c >> 4, c8 = (c & 15) * 8;
            *(short8*)&Ks[row][c8] =
                *(const short8*)(Kb + ((size_t)b * T + kv0 + row) * HD + c8);
        }
#pragma unroll
        for (int it = 0; it < 4; ++it) {
            int c = tid + it * 256;
            int row = c >> 3, c8 = (c & 7) * 8;
            *(short8*)&Vt[row][c8] =
                *(const short8*)(VtG + (size_t)(b * HD + row) * T + kv0 + c8);
        }
        __syncthreads();

        // S = Q K^T  (16 rows x 64 cols per wave)
        f32x4 sa[4];
#pragma unroll
        for (int j = 0; j < 4; ++j) sa[j] = (f32x4)0.0f;
#pragma unroll
        for (int ks = 0; ks < 4; ++ks) {
#pragma unroll
            for (int j = 0; j < 4; ++j) {
                short8 bf = *(const short8*)&Ks[j * 16 + lo][ks * 32 + hi * 8];
                sa[j] = __builtin_amdgcn_mfma_f32_16x16x32_bf16(qf[ks], bf, sa[j], 0, 0, 0);
            }
        }

        const bool diag = (t == qt);
        float alpha[4];
#pragma unroll
        for (int r = 0; r < 4; ++r) {
            const int qrow = qrow_base + r;
            float rm = -1e30f;
#pragma unroll
            for (int j = 0; j < 4; ++j) {
                float v = sa[j][r] * scale2;
                if (diag) {
                    int kv = kv0 + j * 16 + lo;
                    v = (kv <= qrow) ? v : -1e30f;
                }
                sa[j][r] = v;
                rm = fmaxf(rm, v);
            }
            rm = fmaxf(rm, __shfl_xor(rm, 1));
            rm = fmaxf(rm, __shfl_xor(rm, 2));
            rm = fmaxf(rm, __shfl_xor(rm, 4));
            rm = fmaxf(rm, __shfl_xor(rm, 8));
            float mn = fmaxf(mrow[r], rm);
            alpha[r] = exp2f(mrow[r] - mn);
            mrow[r] = mn;
            float ls = 0.0f;
#pragma unroll
            for (int j = 0; j < 4; ++j) {
                float p = exp2f(sa[j][r] - mn);
                sa[j][r] = p;
                ls += p;
            }
            ls += __shfl_xor(ls, 1);
            ls += __shfl_xor(ls, 2);
            ls += __shfl_xor(ls, 4);
            ls += __shfl_xor(ls, 8);
            lrow[r] = lrow[r] * alpha[r] + ls;
        }
#pragma unroll
        for (int n = 0; n < 8; ++n)
#pragma unroll
            for (int r = 0; r < 4; ++r) o[n][r] *= alpha[r];

#pragma unroll
        for (int r = 0; r < 4; ++r)
#pragma unroll
            for (int j = 0; j < 4; ++j)
                Ps[w * 16 + hi * 4 + r][j * 16 + lo] = f2bf(sa[j][r]);
        __syncthreads();

        // O += P V
#pragma unroll
        for (int ks = 0; ks < 2; ++ks) {
            short8 af = *(const short8*)&Ps[w * 16 + lo][ks * 32 + hi * 8];
#pragma unroll
            for (int n = 0; n < 8; ++n) {
                short8 bv = *(const short8*)&Vt[n * 16 + lo][ks * 32 + hi * 8];
                o[n] = __builtin_amdgcn_mfma_f32_16x16x32_bf16(af, bv, o[n], 0, 0, 0);
            }
        }
        __syncthreads();
    }

    if (nsplit == 1) {
#pragma unroll
        for (int n = 0; n < 8; ++n) {
            int h = n * 16 + lo;
#pragma unroll
            for (int r = 0; r < 4; ++r) {
                int row = qrow_base + r;
                out[((size_t)b * T + row) * HD + h] = o[n][r] / lrow[r];
            }
        }
    } else {
        const size_t slot = (size_t)(b * 32 + qt) * 4 + s;
        float* po = part_o + slot * (QB * HD);
#pragma unroll
        for (int n = 0; n < 8; ++n) {
            int h = n * 16 + lo;
#pragma unroll
            for (int r = 0; r < 4; ++r)
                po[(w * 16 + hi * 4 + r) * HD + h] = o[n][r];
        }
        if (lo == 0) {
            float* pm = part_ml + slot * (QB * 2);
#pragma unroll
            for (int r = 0; r < 4; ++r) {
                pm[(w * 16 + hi * 4 + r) * 2 + 0] = mrow[r];
                pm[(w * 16 + hi * 4 + r) * 2 + 1] = lrow[r];
            }
        }
    }
}

// ---------------------------------------------------------------------------
// Kernel 3: combine split partials (only q-tiles 8..31 have >1 split)
// ---------------------------------------------------------------------------
__global__ __launch_bounds__(256) void attn_combine(
    const float* __restrict__ part_o, const float* __restrict__ part_ml,
    float* __restrict__ out)
{
    const int qt = 8 + blockIdx.x;     // 8..31
    const int b  = blockIdx.y;
    const int ns = qt / 8 + 1;         // 2..4
    const int tid = threadIdx.x;
    const int row = tid >> 2;          // 0..63
    const int c0  = (tid & 3) * 32;
    const size_t slot0 = (size_t)(b * 32 + qt) * 4;

    float mi[4], li[4];
    float m = -1e30f;
#pragma unroll 4
    for (int i = 0; i < ns; ++i) {
        mi[i] = part_ml[(slot0 + i) * (QB * 2) + row * 2 + 0];
        li[i] = part_ml[(slot0 + i) * (QB * 2) + row * 2 + 1];
        m = fmaxf(m, mi[i]);
    }
    float L = 0.0f, f[4];
#pragma unroll 4
    for (int i = 0; i < ns; ++i) {
        f[i] = exp2f(mi[i] - m);
        L += li[i] * f[i];
    }
    const float inv = 1.0f / L;

    float4 acc[8];
#pragma unroll
    for (int k = 0; k < 8; ++k) acc[k] = make_float4(0.f, 0.f, 0.f, 0.f);
#pragma unroll 4
    for (int i = 0; i < ns; ++i) {
        const float4* src = (const float4*)(part_o + (slot0 + i) * (QB * HD) + row * HD + c0);
#pragma unroll
        for (int k = 0; k < 8; ++k) {
            float4 v = src[k];
            acc[k].x += f[i] * v.x; acc[k].y += f[i] * v.y;
            acc[k].z += f[i] * v.z; acc[k].w += f[i] * v.w;
        }
    }
    float4* dst = (float4*)(out + ((size_t)b * T + qt * QB + row) * HD + c0);
#pragma unroll
    for (int k = 0; k < 8; ++k) {
        float4 v = acc[k];
        dst[k] = make_float4(v.x * inv, v.y * inv, v.z * inv, v.w * inv);
    }
}

// ---------------------------------------------------------------------------
extern "C" void kernel_launch(void* const* d_in, const int* in_sizes, int n_in,
                              void* d_out, int out_size, void* d_ws, size_t ws_size,
                              hipStream_t stream)
{
    const float* x  = (const float*)d_in[0];
    const float* Wq = (const float*)d_in[1];
    const float* Wk = (const float*)d_in[2];
    const float* Wv = (const float*)d_in[3];
    float* out = (float*)d_out;

    // ws layout (bytes)
    const size_t off_Wb = 0;
    const size_t off_Q  = off_Wb + (size_t)NW * EMB * 2;        // 1.5 MB
    const size_t off_K  = off_Q  + (size_t)M * HD * 2;          // +4 MB
    const size_t off_V  = off_K  + (size_t)M * HD * 2;
    const size_t off_po = off_V  + (size_t)M * HD * 2;
    const size_t off_ml = off_po + (size_t)1024 * QB * HD * 4;  // 32 MB partials
    const size_t total  = off_ml + (size_t)1024 * QB * 2 * 4;

    char* ws = (char*)d_ws;
    unsigned short* Wb  = (unsigned short*)(ws + off_Wb);
    unsigned short* Qb  = (unsigned short*)(ws + off_Q);
    unsigned short* Kb  = (unsigned short*)(ws + off_K);
    unsigned short* VtG = (unsigned short*)(ws + off_V);
    float* part_o  = (float*)(ws + off_po);
    float* part_ml = (float*)(ws + off_ml);

    const int use_split = (ws_size >= total) ? 1 : 0;

    conv_w<<<dim3((NW * EMB) / (256 * 8)), 256, 0, stream>>>(Wq, Wk, Wv, Wb);
    qkv_proj<<<dim3(M / PBM), 256, 0, stream>>>(x, Wb, Qb, Kb, VtG);
    attn_fwd<<<dim3(use_split ? 80 : 32, B), 256, 0, stream>>>(
        Qb, Kb, VtG, out, part_o, part_ml, use_split);
    if (use_split)
        attn_combine<<<dim3(24, B), 256, 0, stream>>>(part_o, part_ml, out);
}